// Round 9
// baseline (198.864 us; speedup 1.0000x reference)
//
#include <hip/hip_runtime.h>

namespace {
constexpr int Sdim = 128;
constexpr int Tdim = 64;
constexpr int U2c  = 16;
constexpr int PT   = 32;                 // pixel locations per block (128B yt rows)
constexpr int NTHREADS = 1024;           // 16 waves/block; 2 blocks/CU -> 32 waves/CU
constexpr int PP = Sdim * Sdim;          // 16384 pixels
constexpr int TQ = 16;                   // t-steps staged per phase (LDS = 32 KiB)
constexpr int NSTG = Tdim / TQ;          // 4 stages
}

// (1024,8): min 8 waves/EU -> 2 blocks/CU -> VGPR cap 64. Audit: acc 32 + ring 8
// + sreg 8 + addr ~14 = ~62. This is the occupancy lever: 16 -> 32 waves/CU with
// the per-CU traffic (HBM, LDS bytes) of the best kernel (R4) unchanged.
__global__ __launch_bounds__(NTHREADS, 8)
void upscale_fused(const float* __restrict__ yt,
                   const float* __restrict__ wgt,
                   const float* __restrict__ bias,
                   float* __restrict__ out)
{
    // layout [t_local][u][p ^ (2*t_local)] — identical to R4 (numerically proven).
    __shared__ float wlds[TQ * U2c * PT];   // 32 KiB, single-buffered

    const int tid   = threadIdx.x;
    const int p_blk = blockIdx.x * PT;

    const int pg = tid & 15;            // 2 pixels: p0, p0+1
    const int b2 = (tid >> 4) & 31;     // b in {b2, b2+32}
    const int ug = tid >> 9;            // u half: u in [ug*8, ug*8+8)
    const int p0 = p_blk + pg * 2;

    const float4* wgt4 = reinterpret_cast<const float4*>(wgt);

    // ---- stage weights for t in [stg*16, stg*16+16): 2 float4/thread -------------
    auto stage = [&](int stg) {
        #pragma unroll
        for (int i = 0; i < 2; ++i) {
            const int f = i * NTHREADS + tid;    // 0..2047 float4s of the 32KB tile
            const int r = f >> 6;                // p row 0..31
            const int c = f & 63;                // float4 within the 1KB p-row
            const float4 v = wgt4[(size_t)(p_blk + r) * 256 + (size_t)stg * 64 + c];
            const int tw = c >> 2;               // t_local 0..15
            const int uq = c & 3;                // u quad
            const int col = r ^ (2 * tw);        // float2-preserving XOR swizzle
            float* dst = &wlds[(tw * U2c + uq * 4) * PT + col];
            dst[0 * PT] = v.x;  dst[1 * PT] = v.y;
            dst[2 * PT] = v.z;  dst[3 * PT] = v.w;
        }
    };

    stage(0);

    // ---- init acc with bias (identical for both b) -------------------------------
    float acc[2][2][8];   // [bi][jp][u_local]
    #pragma unroll
    for (int jp = 0; jp < 2; ++jp) {
        const float* bp = bias + (size_t)(p0 + jp) * U2c + ug * 8;
        const float4 q0 = *reinterpret_cast<const float4*>(bp);
        const float4 q1 = *reinterpret_cast<const float4*>(bp + 4);
        const float bb[8] = {q0.x,q0.y,q0.z,q0.w, q1.x,q1.y,q1.z,q1.w};
        #pragma unroll
        for (int j = 0; j < 8; ++j) { acc[0][jp][j] = bb[j]; acc[1][jp][j] = bb[j]; }
    }

    // ---- yt: float2 per (b,t); wave = 4 x 128B segments, 512B/instr (R4 shape) ---
    const float* y0b = yt + (size_t)b2 * ((size_t)Tdim * PP) + p0;
    const float* y1b = y0b + (size_t)32 * Tdim * PP;
    float2 yc0, yc1, yn0, yn1;
    yc0 = *reinterpret_cast<const float2*>(y0b);
    yc1 = *reinterpret_cast<const float2*>(y1b);
    yn0 = *reinterpret_cast<const float2*>(y0b + PP);
    yn1 = *reinterpret_cast<const float2*>(y1b + PP);

    auto step = [&](const float2& ya, const float2& yb, int tl) {
        const float* wrow = &wlds[((pg * 2) ^ (2 * tl)) + tl * (U2c * PT) + (ug * 8) * PT];
        #pragma unroll
        for (int u = 0; u < 8; ++u) {
            const float2 wv = *reinterpret_cast<const float2*>(wrow + u * PT);
            acc[0][0][u] = fmaf(ya.x, wv.x, acc[0][0][u]);
            acc[0][1][u] = fmaf(ya.y, wv.y, acc[0][1][u]);
            acc[1][0][u] = fmaf(yb.x, wv.x, acc[1][0][u]);
            acc[1][1][u] = fmaf(yb.y, wv.y, acc[1][1][u]);
        }
    };

    __syncthreads();   // stage(0) visible

    #pragma unroll 1
    for (int stg = 0; stg < NSTG; ++stg) {
        #pragma unroll 1
        for (int tq = 0; tq < TQ; tq += 2) {
            const int tg = stg * TQ + tq;
            step(yc0, yc1, tq);
            if (tg + 2 < Tdim) {
                yc0 = *reinterpret_cast<const float2*>(y0b + (size_t)(tg + 2) * PP);
                yc1 = *reinterpret_cast<const float2*>(y1b + (size_t)(tg + 2) * PP);
            }
            step(yn0, yn1, tq + 1);
            if (tg + 3 < Tdim) {
                yn0 = *reinterpret_cast<const float2*>(y0b + (size_t)(tg + 3) * PP);
                yn1 = *reinterpret_cast<const float2*>(y1b + (size_t)(tg + 3) * PP);
            }
        }
        if (stg + 1 < NSTG) {
            __syncthreads();    // all waves done reading current stage
            stage(stg + 1);
            __syncthreads();    // new stage visible
        }
    }

    // ---- epilogue: pixel-shuffle scatter, 16B contiguous per store ---------------
    const int s1   = p_blk / Sdim;
    const int s2_0 = p_blk % Sdim;

    #pragma unroll
    for (int bi = 0; bi < 2; ++bi) {
        const int b = b2 + bi * 32;
        float* ob = out + (size_t)b * (512 * 512);
        #pragma unroll
        for (int jp = 0; jp < 2; ++jp) {
            const int c0 = (s2_0 + pg * 2 + jp) * 4;
            #pragma unroll
            for (int half = 0; half < 2; ++half) {
                const int r = s1 * 4 + ug * 2 + half;
                float4 v;
                v.x = acc[bi][jp][half * 4 + 0];
                v.y = acc[bi][jp][half * 4 + 1];
                v.z = acc[bi][jp][half * 4 + 2];
                v.w = acc[bi][jp][half * 4 + 3];
                *reinterpret_cast<float4*>(ob + (size_t)r * 512 + c0) = v;
            }
        }
    }
}

extern "C" void kernel_launch(void* const* d_in, const int* in_sizes, int n_in,
                              void* d_out, int out_size, void* d_ws, size_t ws_size,
                              hipStream_t stream)
{
    const float* yt   = (const float*)d_in[0];
    const float* wgt  = (const float*)d_in[1];
    const float* bias = (const float*)d_in[2];
    float* outp       = (float*)d_out;

    dim3 grid(PP / PT);     // 512 blocks x 1024 threads
    dim3 block(NTHREADS);
    hipLaunchKernelGGL(upscale_fused, grid, block, 0, stream, yt, wgt, bias, outp);
}

// Round 10
// 107.283 us; speedup vs baseline: 1.8536x; 1.8536x over previous
//
#include <hip/hip_runtime.h>

namespace {
constexpr int Sdim = 128;
constexpr int Tdim = 64;
constexpr int U2c  = 16;
constexpr int PT   = 32;                 // pixel locations per block (128B yt rows)
constexpr int NTHREADS = 256;            // 4 waves/block; 2 blocks/CU -> 8 waves/CU
constexpr int PP = Sdim * Sdim;          // 16384 pixels
constexpr int TQ = 16;                   // t-steps staged per phase (LDS = 32 KiB)
constexpr int NSTG = Tdim / TQ;          // 4 stages
}

// (256,2): VGPR cap 256, need ~190 -> no clamp-spill (R2/R9 lesson). Mapping
// 2p x 4b x 16u: LDS bytes per FMA halve vs R4 (4/#b rule) -> LDS pipe 41->20us,
// with the R4-proven yt request shape (4x128B segments, 512B/instr, no dup)
// and LDS layout byte-identical.
__global__ __launch_bounds__(NTHREADS, 2)
void upscale_fused(const float* __restrict__ yt,
                   const float* __restrict__ wgt,
                   const float* __restrict__ bias,
                   float* __restrict__ out)
{
    // layout [t_local][u][p ^ (2*t_local)] — identical to R4 (numerically proven).
    __shared__ float wlds[TQ * U2c * PT];   // 32 KiB, single-buffered

    const int tid   = threadIdx.x;
    const int p_blk = blockIdx.x * PT;

    const int pg = tid & 15;            // 2 pixels: p0, p0+1
    const int bq = tid >> 4;            // 0..15: b = bq + 16k, k = 0..3
    const int p0 = p_blk + pg * 2;

    const float4* wgt4 = reinterpret_cast<const float4*>(wgt);

    // ---- stage weights for t in [stg*16, stg*16+16): 8 float4/thread -------------
    auto stage = [&](int stg) {
        #pragma unroll
        for (int i = 0; i < 8; ++i) {
            const int f = i * NTHREADS + tid;    // 0..2047 float4s of the 32KB tile
            const int r = f >> 6;                // p row 0..31
            const int c = f & 63;                // float4 within the 1KB p-row
            const float4 v = wgt4[(size_t)(p_blk + r) * 256 + (size_t)stg * 64 + c];
            const int tw = c >> 2;               // t_local 0..15
            const int uq = c & 3;                // u quad
            const int col = r ^ (2 * tw);        // float2-preserving XOR swizzle
            float* dst = &wlds[(tw * U2c + uq * 4) * PT + col];
            dst[0 * PT] = v.x;  dst[1 * PT] = v.y;
            dst[2 * PT] = v.z;  dst[3 * PT] = v.w;
        }
    };

    stage(0);

    // ---- init acc with bias (identical for all 4 b) ------------------------------
    float acc[4][2][16];   // [k][jp][u]
    #pragma unroll
    for (int jp = 0; jp < 2; ++jp) {
        const float* bp = bias + (size_t)(p0 + jp) * U2c;
        #pragma unroll
        for (int q = 0; q < 4; ++q) {
            const float4 v = *reinterpret_cast<const float4*>(bp + q * 4);
            #pragma unroll
            for (int k = 0; k < 4; ++k) {
                acc[k][jp][q * 4 + 0] = v.x;  acc[k][jp][q * 4 + 1] = v.y;
                acc[k][jp][q * 4 + 2] = v.z;  acc[k][jp][q * 4 + 3] = v.w;
            }
        }
    }

    // ---- yt: float2 per (b,t); wave = 4 x 128B segments, 512B/instr, no dup ------
    const float* ybase = yt + (size_t)bq * ((size_t)Tdim * PP) + p0;
    auto ldy = [&](int t, float2* dst) {
        #pragma unroll
        for (int k = 0; k < 4; ++k)
            dst[k] = *reinterpret_cast<const float2*>(
                ybase + (size_t)k * 16 * Tdim * PP + (size_t)t * PP);
    };

    auto step = [&](const float2* y, int tl) {
        const float* wrow = &wlds[tl * (U2c * PT) + ((pg * 2) ^ (2 * tl))];
        #pragma unroll
        for (int u = 0; u < 16; ++u) {
            const float2 wv = *reinterpret_cast<const float2*>(wrow + u * PT);
            #pragma unroll
            for (int k = 0; k < 4; ++k) {
                acc[k][0][u] = fmaf(y[k].x, wv.x, acc[k][0][u]);
                acc[k][1][u] = fmaf(y[k].y, wv.y, acc[k][1][u]);
            }
        }
    };

    // ---- depth-2 ping-pong yt ring (static indexing) -----------------------------
    float2 yc[4], yn[4];
    ldy(0, yc);
    ldy(1, yn);

    __syncthreads();   // stage(0) visible

    #pragma unroll 1
    for (int stg = 0; stg < NSTG; ++stg) {
        #pragma unroll 1
        for (int tq = 0; tq < TQ; tq += 2) {
            const int tg = stg * TQ + tq;
            step(yc, tq);
            if (tg + 2 < Tdim) ldy(tg + 2, yc);
            step(yn, tq + 1);
            if (tg + 3 < Tdim) ldy(tg + 3, yn);
        }
        if (stg + 1 < NSTG) {
            __syncthreads();    // all waves done reading current stage
            stage(stg + 1);
            __syncthreads();    // new stage visible
        }
    }

    // ---- epilogue: pixel-shuffle scatter, 16B contiguous per store ---------------
    const int s1   = p_blk / Sdim;
    const int s2_0 = p_blk % Sdim;

    #pragma unroll
    for (int k = 0; k < 4; ++k) {
        const int b = bq + 16 * k;
        float* ob = out + (size_t)b * (512 * 512);
        #pragma unroll
        for (int jp = 0; jp < 2; ++jp) {
            const int c0 = (s2_0 + pg * 2 + jp) * 4;
            #pragma unroll
            for (int u1 = 0; u1 < 4; ++u1) {
                const int r = s1 * 4 + u1;
                float4 v;
                v.x = acc[k][jp][u1 * 4 + 0];
                v.y = acc[k][jp][u1 * 4 + 1];
                v.z = acc[k][jp][u1 * 4 + 2];
                v.w = acc[k][jp][u1 * 4 + 3];
                *reinterpret_cast<float4*>(ob + (size_t)r * 512 + c0) = v;
            }
        }
    }
}

extern "C" void kernel_launch(void* const* d_in, const int* in_sizes, int n_in,
                              void* d_out, int out_size, void* d_ws, size_t ws_size,
                              hipStream_t stream)
{
    const float* yt   = (const float*)d_in[0];
    const float* wgt  = (const float*)d_in[1];
    const float* bias = (const float*)d_in[2];
    float* outp       = (float*)d_out;

    dim3 grid(PP / PT);     // 512 blocks x 256 threads
    dim3 block(NTHREADS);
    hipLaunchKernelGGL(upscale_fused, grid, block, 0, stream, yt, wgt, bias, outp);
}